// Round 16
// baseline (1705.108 us; speedup 1.0000x reference)
//
#include <hip/hip_runtime.h>
#include <math.h>

#define BB    256
#define TT    2048
#define DZc   256
#define PSTR  257              // padded part row stride (floats)
#define CLIPV 5.0f

__device__ __forceinline__ float softplus_f(float s) {
    return fmaxf(s, 0.0f) + log1pf(expf(-fabsf(s)));
}

// uniform broadcast of lane `c`'s value via v_readlane (c in 0..15 here)
__device__ __forceinline__ float rl(float v, int c) {
    return __builtin_bit_cast(float,
        __builtin_amdgcn_readlane(__builtin_bit_cast(int, v), c));
}

// 16 waves (1024 thr), 4 waves/SIMD: W tile 64 floats/lane fits 128-VGPR
// budget; 4 independent waves per SIMD hide barrier/LDS/dep latency.
__global__ __launch_bounds__(1024)
__attribute__((amdgpu_waves_per_eu(4, 4)))
void plrnn_scan(const float* __restrict__ xin,   // (B,T,1)
                const float* __restrict__ z0,    // (B,DZ)
                const float* __restrict__ AW,    // (DZ,DZ)
                const float* __restrict__ h,     // (DZ)
                const float* __restrict__ Cw,    // (DZ,1)
                const float* __restrict__ Rw,    // (1,DZ)
                const float* __restrict__ Rb,    // (1)
                float* __restrict__ out)         // (B,T,1)
{
    __shared__ float part[2][16][PSTR]; // 32.9KB double-buffered partials
    __shared__ float xs[TT];            // 8KB input sequence
    __shared__ float ypr[256][17];      // 17.4KB y ring (padded)

    const int tid   = threadIdx.x;
    const int b     = blockIdx.x;
    const int l     = tid & 63;
    const int w     = tid >> 6;         // wave 0..15
    const int col0  = w * 16;           // this wave's 16-column block
    const int q     = l >> 4;           // lane quarter 0..3
    const int myrow = col0 + (l & 15);  // row this lane updates (replicated x4)

    // ---- one-time: W[4l..4l+3][col0..col0+15] into 64 registers, diag=0 ----
    float wv[4][16];
    #pragma unroll
    for (int i = 0; i < 4; ++i) {
        const int row = 4 * l + i;
        const float* src = AW + row * DZc + col0;
        #pragma unroll
        for (int p = 0; p < 4; ++p) {
            float4 v = *reinterpret_cast<const float4*>(src + 4 * p);
            const int c = col0 + 4 * p;
            if (c + 0 == row) v.x = 0.0f;
            if (c + 1 == row) v.y = 0.0f;
            if (c + 2 == row) v.z = 0.0f;
            if (c + 3 == row) v.w = 0.0f;
            wv[i][4*p+0] = v.x; wv[i][4*p+1] = v.y;
            wv[i][4*p+2] = v.z; wv[i][4*p+3] = v.w;
        }
    }
    #pragma unroll
    for (int i = 0; i < 4; ++i)
        #pragma unroll
        for (int c = 0; c < 16; c += 4)
            asm volatile("" : "+v"(wv[i][c]), "+v"(wv[i][c+1]),
                              "+v"(wv[i][c+2]), "+v"(wv[i][c+3]));

    const float a_i  = AW[myrow * DZc + myrow];
    const float h_i  = h[myrow];
    const float cw_i = Cw[myrow];
    const float rw_i = Rw[myrow];
    const float rb   = Rb[0];

    #pragma unroll
    for (int k = 0; k < TT / 1024; ++k)
        xs[tid + 1024 * k] = xin[b * TT + tid + 1024 * k];

    float z = z0[b * DZc + myrow];      // replicated in all 4 quarters
    float r = fmaxf(z, 0.f);
    float u = z * rw_i;
    __syncthreads();                    // xs ready

    // iteration t: state z=Z_t; computes Z_{t+1}; emits y_{t-1}
    for (int t = 0; t < TT; ++t) {
        // ---- y partial for t-1: width-16 butterfly (DS pipe) ----
        float yac = u;
        yac += __shfl_xor(yac, 8, 16);
        yac += __shfl_xor(yac, 4, 16);
        yac += __shfl_xor(yac, 2, 16);
        yac += __shfl_xor(yac, 1, 16);

        // ---- phase 1: 16-col partial matvec via readlane broadcast ----
        float acc0 = 0.f, acc1 = 0.f, acc2 = 0.f, acc3 = 0.f;
        #pragma unroll
        for (int c = 0; c < 16; ++c) {
            const float rc = rl(r, c);     // relu(z)[col0+c] from lane c
            acc0 = fmaf(wv[0][c], rc, acc0);
            acc1 = fmaf(wv[1][c], rc, acc1);
            acc2 = fmaf(wv[2][c], rc, acc2);
            acc3 = fmaf(wv[3][c], rc, acc3);
        }
        if (l == 0 && t > 0) ypr[(t - 1) & 255][w] = yac;
        *reinterpret_cast<float4*>(&part[t & 1][w][4 * l]) =
            make_float4(acc0, acc1, acc2, acc3);
        __syncthreads();                   // single barrier per step

        // ---- phase 2: quarter q sums partials 4q..4q+3 for row myrow,
        //      then 2-level cross-quarter combine; all lanes get full sum ----
        const float* pp = &part[t & 1][0][myrow];
        float s0 = pp[(4*q+0)*PSTR] + pp[(4*q+1)*PSTR];
        float s1 = pp[(4*q+2)*PSTR] + pp[(4*q+3)*PSTR];
        float sq = s0 + s1;
        sq += __shfl_xor(sq, 16, 64);
        sq += __shfl_xor(sq, 32, 64);
        float zi = fmaf(a_i, z, sq);
        zi = fmaf(xs[t], cw_i, zi + h_i);
        zi = fminf(fmaxf(zi, -CLIPV), CLIPV);
        z = zi;
        r = fmaxf(zi, 0.f);
        u = zi * rw_i;

        // ---- amortized flush: 128 y's, coalesced, every 128 steps ----
        if ((t & 127) == 0 && t && tid < 128) {
            const int base = t - 128;
            const float* yy = &ypr[(base + tid) & 255][0];
            float4 A = *reinterpret_cast<const float4*>(yy);
            float4 Bv = *reinterpret_cast<const float4*>(yy + 4);
            float4 C = *reinterpret_cast<const float4*>(yy + 8);
            float4 D = *reinterpret_cast<const float4*>(yy + 12);
            float s16 = (((A.x + A.y) + (A.z + A.w)) + ((Bv.x + Bv.y) + (Bv.z + Bv.w)))
                      + (((C.x + C.y) + (C.z + C.w)) + ((D.x + D.y) + (D.z + D.w)));
            out[(size_t)b * TT + base + tid] = softplus_f(s16 + rb);
        }
    }

    // ---- epilogue: y_{T-1} from Z_T, then flush last 128 ----
    {
        float yac = u;
        yac += __shfl_xor(yac, 8, 16);
        yac += __shfl_xor(yac, 4, 16);
        yac += __shfl_xor(yac, 2, 16);
        yac += __shfl_xor(yac, 1, 16);
        if (l == 0) ypr[(TT - 1) & 255][w] = yac;
    }
    __syncthreads();
    if (tid < 128) {
        const int base = TT - 128;
        const float* yy = &ypr[(base + tid) & 255][0];
        float4 A = *reinterpret_cast<const float4*>(yy);
        float4 Bv = *reinterpret_cast<const float4*>(yy + 4);
        float4 C = *reinterpret_cast<const float4*>(yy + 8);
        float4 D = *reinterpret_cast<const float4*>(yy + 12);
        float s16 = (((A.x + A.y) + (A.z + A.w)) + ((Bv.x + Bv.y) + (Bv.z + Bv.w)))
                  + (((C.x + C.y) + (C.z + C.w)) + ((D.x + D.y) + (D.z + D.w)));
        out[(size_t)b * TT + base + tid] = softplus_f(s16 + rb);
    }
}

extern "C" void kernel_launch(void* const* d_in, const int* in_sizes, int n_in,
                              void* d_out, int out_size, void* d_ws, size_t ws_size,
                              hipStream_t stream) {
    const float* xin = (const float*)d_in[0];
    const float* z0v = (const float*)d_in[1];
    const float* AW  = (const float*)d_in[2];
    const float* hv  = (const float*)d_in[3];
    const float* Cw  = (const float*)d_in[4];
    const float* Rw  = (const float*)d_in[5];
    const float* Rb  = (const float*)d_in[6];
    float* out = (float*)d_out;
    plrnn_scan<<<BB, 1024, 0, stream>>>(xin, z0v, AW, hv, Cw, Rw, Rb, out);
}